// Round 4
// baseline (144.890 us; speedup 1.0000x reference)
//
#include <hip/hip_runtime.h>
#include <cstdint>
#include <cstddef>

#define DIM 256
#define NSRC 8192
#define NCLS 64
#define KSTEPS 8          // K=256 / 32
#define INV_TAU (1.0f / 0.07f)
#define EPITCH 136        // epilogue LDS pitch (ushorts): 272B rows, 16B-aligned

typedef __attribute__((ext_vector_type(8))) short bf16x8;
typedef __attribute__((ext_vector_type(4))) float f32x4;
typedef unsigned char uchar;

// ---------------------------------------------------------------- helpers ---
__device__ __forceinline__ ushort f2bf_rne(float f) {
    uint u = __float_as_uint(f);
    uint r = u + 0x7fff + ((u >> 16) & 1);
    return (ushort)(r >> 16);
}
// order-preserving bf16 <-> u16 ordinal (monotone increasing with value)
__device__ __forceinline__ uint bf2ord(uint u) {
    return u ^ (0x8000u + (u >> 15) * 0x7FFFu);
}
__device__ __forceinline__ float ord2f(uint o) {
    uint u = (o & 0x8000u) ? (o ^ 0x8000u) : (~o & 0xFFFFu);
    return __uint_as_float(u << 16);
}

__device__ __forceinline__ void gload_lds16(const void* g, void* l) {
    __builtin_amdgcn_global_load_lds((const __attribute__((address_space(1))) void*)g,
                                     (__attribute__((address_space(3))) void*)l,
                                     16, 0, 0);
}

// ------------------------------------------------ l2norm -> bf16 (fused) ----
// one WAVE per row; waves [0, nA): A rows; [nA, nA+nB): B rows
__global__ __launch_bounds__(256) void l2bf2_k(const float* __restrict__ inA,
                                               ushort* __restrict__ outA, int nA,
                                               const float* __restrict__ inB,
                                               ushort* __restrict__ outB, int nB) {
    const int w = (blockIdx.x * 256 + threadIdx.x) >> 6;   // global wave id = row
    const int lane = threadIdx.x & 63;
    if (w >= nA + nB) return;
    const float* in;
    ushort* out;
    int row;
    if (w < nA) { in = inA; out = outA; row = w; }
    else        { in = inB; out = outB; row = w - nA; }
    float4 v = *(const float4*)(in + (size_t)row * DIM + lane * 4);
    float ss = v.x * v.x + v.y * v.y + v.z * v.z + v.w * v.w;
#pragma unroll
    for (int d = 1; d < 64; d <<= 1) ss += __shfl_xor(ss, d);
    const float n = fmaxf(sqrtf(ss), 1e-12f);
    ushort4 o;
    o.x = f2bf_rne(v.x / n);
    o.y = f2bf_rne(v.y / n);
    o.z = f2bf_rne(v.z / n);
    o.w = f2bf_rne(v.w / n);
    *(ushort4*)(out + (size_t)row * DIM + lane * 4) = o;
}

// ---------------- one-shot class build: lab8 + cstart + ordered clist -------
__global__ __launch_bounds__(256) void class_build_k(const int* __restrict__ labels,
                                                     uchar* __restrict__ lab8,
                                                     int* __restrict__ cstart,
                                                     int* __restrict__ clist, int n) {
    const int c = blockIdx.x, t = threadIdx.x;
    const int g = c * 256 + t;
    if (g < n) lab8[g] = (uchar)labels[g];

    __shared__ int sl[256], se[256];
    const int per = n >> 8;          // 32
    const int i0 = t * per;
    int less = 0, eq = 0;
    for (int j = 0; j < per; ++j) {
        const int l = labels[i0 + j];
        less += (l < c);
        eq += (l == c);
    }
    sl[t] = less; se[t] = eq;
    __syncthreads();
    for (int s = 1; s < 256; s <<= 1) {
        const int a = (t >= s) ? sl[t - s] : 0;
        const int b = (t >= s) ? se[t - s] : 0;
        __syncthreads();
        sl[t] += a; se[t] += b;
        __syncthreads();
    }
    const int base = sl[255];
    int pos = base + se[t] - eq;     // exclusive scan offset
    for (int j = 0; j < per; ++j) {
        const int i = i0 + j;
        if (labels[i] == c) clist[pos++] = i;
    }
    if (t == 0) cstart[c] = base;
    if (c == 0 && t == 1) cstart[NCLS] = n;
}

// ------------------------------------------------------------- MFMA GEMM ----
// C[M][N] (ord16) = A[M][256]*B[N][256]^T, 128x128 tile, 4 waves.
// B: 4-deep LDS ring (32KB) + raw s_barrier + counted vmcnt.
// A: direct global->VGPR depth-2 rotating prefetch (no LDS, not barrier-
// coupled). LDS block = 34.8KB epilogue tile -> 4 blocks/CU (16 waves).
// XCD-grouped mapping keeps A/B panels L2-resident (18MB fetch).
__global__ __launch_bounds__(256, 4) void gemm_mfma_k(const ushort* __restrict__ A,
                                                      const ushort* __restrict__ B,
                                                      ushort* __restrict__ C,
                                                      int M, int N) {
    // ring: B buffers [0, 32KB); epilogue tile reuses [0, 34816B)
    __shared__ __align__(16) ushort smem[17408];   // 34816 B

    const int tid = threadIdx.x;
    const int lane = tid & 63, wid = tid >> 6;
    const int wr = wid >> 1, wc = wid & 1;        // 2x2 waves, 64x64 each

    // XCD-aware 2D-grouped mapping: grid 64(bn) x 48(bm), 3072 blocks, 8 XCDs.
    const int gx = gridDim.x;                      // 64
    const int bid = blockIdx.y * gx + blockIdx.x;
    const int rowsPerX = gridDim.y >> 3;           // 6
    const int grpW = 8;
    const int grpSize = rowsPerX * grpW;           // 48
    const int xcd = bid & 7;
    const int local = bid >> 3;                    // 0..383
    const int grp = local / grpSize;
    const int within = local % grpSize;
    const int bm = (xcd * rowsPerX + within % rowsPerX) * 128;
    const int bn = (grp * grpW + within / rowsPerX) * 128;

    // ---- B staging source/dest (k-chunk XOR swizzle) ----
    const char* bSrc[2];
    uint ldsOff[2];
#pragma unroll
    for (int it = 0; it < 2; ++it) {
        const int c = it * 256 + tid;          // 16B chunk id 0..511
        const int r = c >> 2;                  // tile row 0..127
        const int ch = c & 3;                  // chunk within row (K dir)
        const int sch = ch ^ ((r >> 1) & 3);   // swizzled source chunk
        bSrc[it] = (const char*)B + (size_t)(bn + r) * (DIM * 2) + sch * 16;
        ldsOff[it] = it * 4096 + (uint)(wid * 1024);
    }

    const int fr = lane & 15, fk = lane >> 4;
    const int swz = (fr >> 1) & 3;
    int idxB[4];
#pragma unroll
    for (int n = 0; n < 4; ++n)
        idxB[n] = (wc * 64 + n * 16 + fr) * 32 + ((fk ^ swz) * 8);

    // ---- A fragments: direct global->VGPR, depth-2 rotating prefetch ----
    const ushort* aPtr[4];
#pragma unroll
    for (int m = 0; m < 4; ++m)
        aPtr[m] = A + (size_t)(bm + wr * 64 + m * 16 + fr) * DIM + fk * 8;

    f32x4 acc[4][4];
#pragma unroll
    for (int m = 0; m < 4; ++m)
#pragma unroll
        for (int n = 0; n < 4; ++n) acc[m][n] = (f32x4){0.f, 0.f, 0.f, 0.f};

    // 2 loads/thread per B stage
#define BSTAGE(b, ks)                                                              \
    {                                                                              \
        _Pragma("unroll") for (int it = 0; it < 2; ++it) {                         \
            gload_lds16(bSrc[it] + (ks) * 64,                                      \
                        (char*)smem + (b) * 8192 + ldsOff[it]);                    \
        }                                                                          \
    }

    bf16x8 av[2][4];
    // prologue stream: B0 B1 A0 B2 A1  (counts for vmcnt below depend on this)
    BSTAGE(0, 0);
    BSTAGE(1, 1);
    asm volatile("" ::: "memory");
#pragma unroll
    for (int m = 0; m < 4; ++m) av[0][m] = *(const bf16x8*)(aPtr[m] + 0 * 32);
    asm volatile("" ::: "memory");
    BSTAGE(2, 2);
    asm volatile("" ::: "memory");
#pragma unroll
    for (int m = 0; m < 4; ++m) av[1][m] = *(const bf16x8*)(aPtr[m] + 1 * 32);

    // per-iter stream: [wait][barrier] B(ks+3) ... MFMA ... A(ks+2)
    // outstanding younger than {B(ks), A(ks)}: B+A groups = 6 in steady state
#pragma unroll
    for (int ks = 0; ks < KSTEPS; ++ks) {
        if (ks < KSTEPS - 2)      { asm volatile("s_waitcnt vmcnt(6)" ::: "memory"); }
        else if (ks == KSTEPS - 2){ asm volatile("s_waitcnt vmcnt(4)" ::: "memory"); }
        else                      { asm volatile("s_waitcnt vmcnt(0)" ::: "memory"); }
        __builtin_amdgcn_s_barrier();          // all waves' B stage-ks landed
        asm volatile("" ::: "memory");         // no LDS read hoists above barrier

        if (ks + 3 < KSTEPS) BSTAGE((ks + 3) & 3, ks + 3);  // refill ring slot
        asm volatile("" ::: "memory");

        const ushort* sBc = smem + (ks & 3) * 4096;
        bf16x8 bv[4];
#pragma unroll
        for (int n = 0; n < 4; ++n) bv[n] = *(const bf16x8*)&sBc[idxB[n]];
#pragma unroll
        for (int m = 0; m < 4; ++m)
#pragma unroll
            for (int n = 0; n < 4; ++n)
                acc[m][n] = __builtin_amdgcn_mfma_f32_16x16x32_bf16(av[ks & 1][m], bv[n], acc[m][n], 0, 0, 0);

        if (ks + 2 < KSTEPS) {
            asm volatile("" ::: "memory");
#pragma unroll
            for (int m = 0; m < 4; ++m)
                av[ks & 1][m] = *(const bf16x8*)(aPtr[m] + (ks + 2) * 32);
        }
    }
#undef BSTAGE

    // ---- epilogue: fragments -> ord16 LDS tile -> coalesced 16B stores ----
    __syncthreads();
#pragma unroll
    for (int m = 0; m < 4; ++m) {
#pragma unroll
        for (int n = 0; n < 4; ++n) {
            const int colb = wc * 64 + n * 16 + fr;
#pragma unroll
            for (int j = 0; j < 4; ++j) {
                const int rowb = wr * 64 + m * 16 + fk * 4 + j;
                smem[rowb * EPITCH + colb] = (ushort)bf2ord((uint)f2bf_rne(acc[m][n][j]));
            }
        }
    }
    __syncthreads();
    const int rr = tid >> 4, cc = (tid & 15) * 8;
#pragma unroll
    for (int it = 0; it < 8; ++it) {
        const int r = it * 16 + rr;
        uint4 v = *(const uint4*)&smem[r * EPITCH + cc];
        *(uint4*)(C + (size_t)(bm + r) * N + bn + cc) = v;
    }
}

// ---------------- wave-per-target: depth-4 scan + s1 + exact-detect ----------
// sim holds ord16. Keys: u32 = ord<<16 | (8191-idx) -> umax == (val desc, idx asc)
__global__ __launch_bounds__(256) void assign_score_w(const ushort* __restrict__ sim,
                                                      const int* __restrict__ labels,
                                                      const uchar* __restrict__ lab8,
                                                      const int* __restrict__ cstart,
                                                      const int* __restrict__ clist,
                                                      float* __restrict__ scores_out,
                                                      float* __restrict__ logt_out) {
    const int lane = threadIdx.x & 63, wid = threadIdx.x >> 6;
    const int t = blockIdx.x * 4 + wid;
    const ushort* row = sim + (size_t)t * NSRC;

    uint k0 = 0, k1 = 0, k2 = 0, k3 = 0, k4 = 0, k5 = 0, k6 = 0, k7 = 0;
    float s1 = 0.f;

#define CH4(u16, idx)                                                   \
    {                                                                   \
        uint uu = (uint)(u16);                                          \
        s1 += __expf(fmaf(ord2f(uu), INV_TAU, -INV_TAU));               \
        uint nk = (uu << 16) | (uint)(8191 - (idx));                    \
        uint q;                                                         \
        q = max(k0, nk); nk = min(k0, nk); k0 = q;                      \
        q = max(k1, nk); nk = min(k1, nk); k1 = q;                      \
        q = max(k2, nk); nk = min(k2, nk); k2 = q;                      \
        k3 = max(k3, nk);                                               \
    }
#define CH8(u16, idx)                                                   \
    {                                                                   \
        uint nk = (((uint)(u16)) << 16) | (uint)(8191 - (idx));         \
        uint q;                                                         \
        q = max(k0, nk); nk = min(k0, nk); k0 = q;                      \
        q = max(k1, nk); nk = min(k1, nk); k1 = q;                      \
        q = max(k2, nk); nk = min(k2, nk); k2 = q;                      \
        q = max(k3, nk); nk = min(k3, nk); k3 = q;                      \
        q = max(k4, nk); nk = min(k4, nk); k4 = q;                      \
        q = max(k5, nk); nk = min(k5, nk); k5 = q;                      \
        q = max(k6, nk); nk = min(k6, nk); k6 = q;                      \
        k7 = max(k7, nk);                                               \
    }
#define MERGE8                                                                     \
    _Pragma("unroll")                                                              \
    for (int d = 1; d < 64; d <<= 1) {                                             \
        uint b0 = __shfl_xor(k0, d), b1 = __shfl_xor(k1, d), b2 = __shfl_xor(k2, d),\
             b3 = __shfl_xor(k3, d), b4 = __shfl_xor(k4, d), b5 = __shfl_xor(k5, d),\
             b6 = __shfl_xor(k6, d), b7 = __shfl_xor(k7, d);                        \
        uint r0 = max(k0, b0);                                                     \
        uint r1 = max(max(min(k0, b0), k1), b1);                                   \
        uint r2 = max(max(min(k0, b1), min(k1, b0)), max(k2, b2));                 \
        uint r3 = max(max(min(k0, b2), min(k1, b1)),                               \
                      max(max(min(k2, b0), k3), b3));                              \
        uint r4 = max(max(max(min(k0, b3), min(k1, b2)),                           \
                          max(min(k2, b1), min(k3, b0))), max(k4, b4));            \
        uint r5 = max(max(max(min(k0, b4), min(k1, b3)),                           \
                          max(min(k2, b2), min(k3, b1))),                          \
                      max(max(min(k4, b0), k5), b5));                              \
        uint r6 = max(max(max(min(k0, b5), min(k1, b4)),                           \
                          max(min(k2, b3), min(k3, b2))),                          \
                      max(max(min(k4, b1), min(k5, b0)), max(k6, b6)));            \
        uint r7 = max(max(max(min(k0, b6), min(k1, b5)),                           \
                          max(min(k2, b4), min(k3, b3))),                          \
                      max(max(min(k4, b2), min(k5, b1)),                           \
                          max(max(min(k6, b0), k7), b7)));                         \
        k0 = r0; k1 = r1; k2 = r2; k3 = r3; k4 = r4; k5 = r5; k6 = r6; k7 = r7;    \
    }

    for (int i0 = lane * 8; i0 < NSRC; i0 += 512) {
        uint4 w = *(const uint4*)(row + i0);
        CH4(w.x & 0xFFFF, i0 + 0); CH4(w.x >> 16, i0 + 1);
        CH4(w.y & 0xFFFF, i0 + 2); CH4(w.y >> 16, i0 + 3);
        CH4(w.z & 0xFFFF, i0 + 4); CH4(w.z >> 16, i0 + 5);
        CH4(w.w & 0xFFFF, i0 + 6); CH4(w.w >> 16, i0 + 7);
    }
    const uint prek3 = k3;
    MERGE8;
    // exact iff every lane's dropped elems (< its pre-merge k3) are <= merged k7
    if (!__all((int)(prek3 <= k7))) {
        k0 = k1 = k2 = k3 = k4 = k5 = k6 = k7 = 0;
        for (int i0 = lane * 8; i0 < NSRC; i0 += 512) {
            uint4 w = *(const uint4*)(row + i0);
            CH8(w.x & 0xFFFF, i0 + 0); CH8(w.x >> 16, i0 + 1);
            CH8(w.y & 0xFFFF, i0 + 2); CH8(w.y >> 16, i0 + 3);
            CH8(w.z & 0xFFFF, i0 + 4); CH8(w.z >> 16, i0 + 5);
            CH8(w.w & 0xFFFF, i0 + 6); CH8(w.w >> 16, i0 + 7);
        }
        MERGE8;
    }
#undef CH4
#undef CH8
#undef MERGE8

    // s1 wave-reduce
#pragma unroll
    for (int d = 1; d < 64; d <<= 1) s1 += __shfl_xor(s1, d);

    // ---- labels of top-8 ----
    const int l0 = labels[8191 - (int)(k0 & 0xFFFF)];
    const int l1 = labels[8191 - (int)(k1 & 0xFFFF)];
    const int l2 = labels[8191 - (int)(k2 & 0xFFFF)];
    const int l3 = labels[8191 - (int)(k3 & 0xFFFF)];
    const int l4 = labels[8191 - (int)(k4 & 0xFFFF)];
    const int l5 = labels[8191 - (int)(k5 & 0xFFFF)];
    const int l6 = labels[8191 - (int)(k6 & 0xFFFF)];
    const int l7 = labels[8191 - (int)(k7 & 0xFFFF)];

    // ---- assigned = min label among modes of top-5 labels ----
    const int c0 = 1 + (l0 == l1) + (l0 == l2) + (l0 == l3) + (l0 == l4);
    const int c1 = (l1 == l0) + 1 + (l1 == l2) + (l1 == l3) + (l1 == l4);
    const int c2 = (l2 == l0) + (l2 == l1) + 1 + (l2 == l3) + (l2 == l4);
    const int c3 = (l3 == l0) + (l3 == l1) + (l3 == l2) + 1 + (l3 == l4);
    const int c4 = (l4 == l0) + (l4 == l1) + (l4 == l2) + (l4 == l3) + 1;
    const int maxc = max(max(max(c0, c1), max(c2, c3)), c4);
    int assigned = 0x7fffffff;
    if (c0 == maxc) assigned = min(assigned, l0);
    if (c1 == maxc) assigned = min(assigned, l1);
    if (c2 == maxc) assigned = min(assigned, l2);
    if (c3 == maxc) assigned = min(assigned, l3);
    if (c4 == maxc) assigned = min(assigned, l4);
    const int aL = assigned;

    // ---- nun: first-4 negatives (exact if <=4 positives in top-8) ----
    const int negcnt = (l0 != aL) + (l1 != aL) + (l2 != aL) + (l3 != aL) +
                       (l4 != aL) + (l5 != aL) + (l6 != aL) + (l7 != aL);
    float nun = 0.f;
    if (negcnt >= 4) {
        int c = 0;
#define NSTEP(kj, lj)                                                       \
        {                                                                   \
            bool take = ((lj) != aL) && (c < 4);                            \
            nun += take ? ord2f((kj) >> 16) : 0.f;                          \
            c += take ? 1 : 0;                                              \
        }
        NSTEP(k0, l0) NSTEP(k1, l1) NSTEP(k2, l2) NSTEP(k3, l3)
        NSTEP(k4, l4) NSTEP(k5, l5) NSTEP(k6, l6) NSTEP(k7, l7)
#undef NSTEP
    } else {
        // rare fallback: full-row top-4 negative chain in ord domain
        uint n0 = 0, n1 = 0, n2 = 0, n3 = 0;
        for (int i0 = lane * 8; i0 < NSRC; i0 += 512) {
            uint4 w = *(const uint4*)(row + i0);
            uint2 lw = *(const uint2*)(lab8 + i0);
#define NEGP(u16, lb)                                                       \
            {                                                               \
                uint x = ((lb) == aL) ? 0u : (uint)(u16);                   \
                uint q;                                                     \
                q = max(n0, x); x = min(n0, x); n0 = q;                     \
                q = max(n1, x); x = min(n1, x); n1 = q;                     \
                q = max(n2, x); x = min(n2, x); n2 = q;                     \
                n3 = max(n3, x);                                            \
            }
            NEGP(w.x & 0xFFFF, (int)(lw.x & 255));
            NEGP(w.x >> 16,    (int)((lw.x >> 8) & 255));
            NEGP(w.y & 0xFFFF, (int)((lw.x >> 16) & 255));
            NEGP(w.y >> 16,    (int)(lw.x >> 24));
            NEGP(w.z & 0xFFFF, (int)(lw.y & 255));
            NEGP(w.z >> 16,    (int)((lw.y >> 8) & 255));
            NEGP(w.w & 0xFFFF, (int)((lw.y >> 16) & 255));
            NEGP(w.w >> 16,    (int)(lw.y >> 24));
#undef NEGP
        }
#pragma unroll
        for (int d = 1; d < 64; d <<= 1) {
            uint b0 = __shfl_xor(n0, d), b1 = __shfl_xor(n1, d),
                 b2 = __shfl_xor(n2, d), b3 = __shfl_xor(n3, d);
            uint r0 = max(n0, b0);
            uint r1 = max(max(min(n0, b0), n1), b1);
            uint r2 = max(max(min(n0, b1), min(n1, b0)), max(n2, b2));
            uint r3 = max(max(min(n0, b2), min(n1, b1)),
                          max(max(min(n2, b0), n3), b3));
            n0 = r0; n1 = r1; n2 = r2; n3 = r3;
        }
        nun = (n0 ? ord2f(n0) : 0.f) + (n1 ? ord2f(n1) : 0.f) +
              (n2 ? ord2f(n2) : 0.f) + (n3 ? ord2f(n3) : 0.f);
    }

    // ---- class-member scan: top-4 positives + sp (gathered, ~128 elems) ----
    const int cs = cstart[aL], ce = cstart[aL + 1];
    float tp0 = -2.f, tp1 = -2.f, tp2 = -2.f, tp3 = -2.f;
    float sp = 0.f;
    for (int p = cs + lane; p < ce; p += 64) {
        const int idx = clist[p];
        float v = ord2f((uint)row[idx]);
        sp += __expf(fmaf(v, INV_TAU, -INV_TAU));
        float x = v, q;
        q = fmaxf(tp0, x); x = fminf(tp0, x); tp0 = q;
        q = fmaxf(tp1, x); x = fminf(tp1, x); tp1 = q;
        q = fmaxf(tp2, x); x = fminf(tp2, x); tp2 = q;
        tp3 = fmaxf(tp3, x);
    }
#pragma unroll
    for (int d = 1; d < 64; d <<= 1) {
        sp += __shfl_xor(sp, d);
        float b0 = __shfl_xor(tp0, d), b1 = __shfl_xor(tp1, d),
              b2 = __shfl_xor(tp2, d), b3 = __shfl_xor(tp3, d);
        float r0 = fmaxf(tp0, b0);
        float r1 = fmaxf(fmaxf(fminf(tp0, b0), tp1), b1);
        float r2 = fmaxf(fmaxf(fminf(tp0, b1), fminf(tp1, b0)), fmaxf(tp2, b2));
        float r3 = fmaxf(fmaxf(fminf(tp0, b2), fminf(tp1, b1)),
                         fmaxf(fmaxf(fminf(tp2, b0), tp3), b3));
        tp0 = r0; tp1 = r1; tp2 = r2; tp3 = r3;
    }

    if (lane == 0) {
        float nln = (tp0 > -1.5f ? tp0 : 0.f) + (tp1 > -1.5f ? tp1 : 0.f) +
                    (tp2 > -1.5f ? tp2 : 0.f) + (tp3 > -1.5f ? tp3 : 0.f);
        scores_out[t] = nln / nun;
        logt_out[t] = logf(sp / s1 + 1e-6f);
    }
}

// --------------------------------------- wave-per-element rank selection ----
__global__ __launch_bounds__(256) void select_topk_w(const float* __restrict__ scores,
                                                     int* __restrict__ selected,
                                                     int n, int k) {
    const int lane = threadIdx.x & 63, wid = threadIdx.x >> 6;
    const int t = blockIdx.x * 4 + wid;
    if (t >= n) return;
    const float st = scores[t];
    int rank = 0;
    for (int j0 = lane * 4; j0 < n; j0 += 256) {
        float4 v = *(const float4*)(scores + j0);
        rank += (v.x > st) || (v.x == st && (j0 + 0) < t);
        rank += (v.y > st) || (v.y == st && (j0 + 1) < t);
        rank += (v.z > st) || (v.z == st && (j0 + 2) < t);
        rank += (v.w > st) || (v.w == st && (j0 + 3) < t);
    }
    for (int d = 1; d < 64; d <<= 1) rank += __shfl_xor(rank, d);
    if (lane == 0) selected[t] = (rank < k) ? 1 : 0;
}

// ----------------------------------------------------------- finalize -------
__global__ __launch_bounds__(256) void finalize_k(const float* __restrict__ logt,
                                                  const int* __restrict__ selected,
                                                  float* __restrict__ out, int n, int k) {
    __shared__ float red[256];
    const int tid = threadIdx.x;
    float s = 0.f;
    for (int i = tid; i < n; i += 256) s += selected[i] ? logt[i] : 0.f;
    red[tid] = s;
    __syncthreads();
    for (int st = 128; st > 0; st >>= 1) {
        if (tid < st) red[tid] += red[tid + st];
        __syncthreads();
    }
    if (tid == 0) out[0] = -red[0] / (float)k;
}

// -------------------------------------------------------------- launch ------
extern "C" void kernel_launch(void* const* d_in, const int* in_sizes, int n_in,
                              void* d_out, int out_size, void* d_ws, size_t ws_size,
                              hipStream_t stream) {
    const float* srcF = (const float*)d_in[0];
    const int* labels = (const int*)d_in[1];
    const float* tgtF = (const float*)d_in[2];
    float* out = (float*)d_out;

    const int n_src = in_sizes[1];            // 8192
    const int d = in_sizes[0] / n_src;        // 256
    const int n_tgt = in_sizes[2] / d;        // 6144
    const int topn = n_tgt * 2 / 3;           // 4096

    char* ws = (char*)d_ws;
    ushort* src2 = (ushort*)ws;  ws += (size_t)n_src * DIM * sizeof(ushort);
    ushort* tgt2 = (ushort*)ws;  ws += (size_t)n_tgt * DIM * sizeof(ushort);
    ushort* sim  = (ushort*)ws;  ws += (size_t)n_tgt * NSRC * sizeof(ushort);
    float* scores = (float*)ws;  ws += (size_t)n_tgt * sizeof(float);
    float* logt   = (float*)ws;  ws += (size_t)n_tgt * sizeof(float);
    int* selected = (int*)ws;    ws += (size_t)n_tgt * sizeof(int);
    int* cstart   = (int*)ws;    ws += (size_t)(NCLS + 1) * sizeof(int);
    int* clist    = (int*)ws;    ws += (size_t)n_src * sizeof(int);
    uchar* lab8   = (uchar*)ws;  ws += (size_t)n_src;

    const int nrows = n_tgt + n_src;          // one wave per row, 4 waves/block
    l2bf2_k<<<(nrows + 3) / 4, 256, 0, stream>>>(tgtF, tgt2, n_tgt, srcF, src2, n_src);
    class_build_k<<<NCLS, 256, 0, stream>>>(labels, lab8, cstart, clist, n_src);

    dim3 grid(n_src / 128, n_tgt / 128);
    gemm_mfma_k<<<grid, 256, 0, stream>>>(tgt2, src2, sim, n_tgt, n_src);

    assign_score_w<<<n_tgt / 4, 256, 0, stream>>>(sim, labels, lab8, cstart, clist,
                                                  scores, logt);
    select_topk_w<<<(n_tgt + 3) / 4, 256, 0, stream>>>(scores, selected, n_tgt, topn);
    finalize_k<<<1, 256, 0, stream>>>(logt, selected, out, n_tgt, topn);
}

// Round 5
// 115.552 us; speedup vs baseline: 1.2539x; 1.2539x over previous
//
#include <hip/hip_runtime.h>
#include <cstdint>
#include <cstddef>

#define DIM 256
#define NSRC 8192
#define NCLS 64
#define KSTEPS 8          // K=256 / 32
#define INV_TAU (1.0f / 0.07f)
#define EPITCH 136        // epilogue LDS pitch (ushorts): 272B rows, 16B-aligned

typedef __attribute__((ext_vector_type(8))) short bf16x8;
typedef __attribute__((ext_vector_type(4))) float f32x4;
typedef unsigned char uchar;

// ---------------------------------------------------------------- helpers ---
__device__ __forceinline__ ushort f2bf_rne(float f) {
    uint u = __float_as_uint(f);
    uint r = u + 0x7fff + ((u >> 16) & 1);
    return (ushort)(r >> 16);
}
// order-preserving bf16 <-> u16 ordinal (monotone increasing with value)
__device__ __forceinline__ uint bf2ord(uint u) {
    return u ^ (0x8000u + (u >> 15) * 0x7FFFu);
}
__device__ __forceinline__ float ord2f(uint o) {
    uint u = (o & 0x8000u) ? (o ^ 0x8000u) : (~o & 0xFFFFu);
    return __uint_as_float(u << 16);
}

__device__ __forceinline__ void gload_lds16(const void* g, void* l) {
    __builtin_amdgcn_global_load_lds((const __attribute__((address_space(1))) void*)g,
                                     (__attribute__((address_space(3))) void*)l,
                                     16, 0, 0);
}

// ------------------------------------------------ l2norm -> bf16 (fused) ----
// one WAVE per row; waves [0, nA): A rows; [nA, nA+nB): B rows
__global__ __launch_bounds__(256) void l2bf2_k(const float* __restrict__ inA,
                                               ushort* __restrict__ outA, int nA,
                                               const float* __restrict__ inB,
                                               ushort* __restrict__ outB, int nB) {
    const int w = (blockIdx.x * 256 + threadIdx.x) >> 6;   // global wave id = row
    const int lane = threadIdx.x & 63;
    if (w >= nA + nB) return;
    const float* in;
    ushort* out;
    int row;
    if (w < nA) { in = inA; out = outA; row = w; }
    else        { in = inB; out = outB; row = w - nA; }
    float4 v = *(const float4*)(in + (size_t)row * DIM + lane * 4);
    float ss = v.x * v.x + v.y * v.y + v.z * v.z + v.w * v.w;
#pragma unroll
    for (int d = 1; d < 64; d <<= 1) ss += __shfl_xor(ss, d);
    const float n = fmaxf(sqrtf(ss), 1e-12f);
    ushort4 o;
    o.x = f2bf_rne(v.x / n);
    o.y = f2bf_rne(v.y / n);
    o.z = f2bf_rne(v.z / n);
    o.w = f2bf_rne(v.w / n);
    *(ushort4*)(out + (size_t)row * DIM + lane * 4) = o;
}

// ---------------- one-shot class build: lab8 + cstart + ordered clist -------
__global__ __launch_bounds__(256) void class_build_k(const int* __restrict__ labels,
                                                     uchar* __restrict__ lab8,
                                                     int* __restrict__ cstart,
                                                     int* __restrict__ clist, int n) {
    const int c = blockIdx.x, t = threadIdx.x;
    const int g = c * 256 + t;
    if (g < n) lab8[g] = (uchar)labels[g];

    __shared__ int sl[256], se[256];
    const int per = n >> 8;          // 32
    const int i0 = t * per;
    int less = 0, eq = 0;
    for (int j = 0; j < per; ++j) {
        const int l = labels[i0 + j];
        less += (l < c);
        eq += (l == c);
    }
    sl[t] = less; se[t] = eq;
    __syncthreads();
    for (int s = 1; s < 256; s <<= 1) {
        const int a = (t >= s) ? sl[t - s] : 0;
        const int b = (t >= s) ? se[t - s] : 0;
        __syncthreads();
        sl[t] += a; se[t] += b;
        __syncthreads();
    }
    const int base = sl[255];
    int pos = base + se[t] - eq;     // exclusive scan offset
    for (int j = 0; j < per; ++j) {
        const int i = i0 + j;
        if (labels[i] == c) clist[pos++] = i;
    }
    if (t == 0) cstart[c] = base;
    if (c == 0 && t == 1) cstart[NCLS] = n;
}

// ------------------------------------------------------------- MFMA GEMM ----
// C[M][N] (ord16) = A[M][256]*B[N][256]^T, 128x128 tile, 4 waves.
// 3-deep LDS ring (48KB: A slots [0,24KB), B slots [24KB,48KB)) + raw
// s_barrier + counted vmcnt. Same prefetch distance as the 4-deep ring (one
// stage in flight past current) but 48KB -> 3 blocks/CU (was 2 at 64KB).
// No launch-bounds VGPR cap (R4 lesson: cap -> spills -> +40MB writes).
// XCD-grouped mapping keeps A/B panels L2-resident (18MB fetch).
__global__ __launch_bounds__(256) void gemm_mfma_k(const ushort* __restrict__ A,
                                                   const ushort* __restrict__ B,
                                                   ushort* __restrict__ C,
                                                   int M, int N) {
    __shared__ __align__(16) ushort smem[24576];   // 48 KB

    const int tid = threadIdx.x;
    const int lane = tid & 63, wid = tid >> 6;
    const int wr = wid >> 1, wc = wid & 1;        // 2x2 waves, 64x64 each

    // XCD-aware 2D-grouped mapping: grid 64(bn) x 48(bm), 3072 blocks, 8 XCDs.
    const int gx = gridDim.x;                      // 64
    const int bid = blockIdx.y * gx + blockIdx.x;
    const int rowsPerX = gridDim.y >> 3;           // 6
    const int grpW = 8;
    const int grpSize = rowsPerX * grpW;           // 48
    const int xcd = bid & 7;
    const int local = bid >> 3;                    // 0..383
    const int grp = local / grpSize;
    const int within = local % grpSize;
    const int bm = (xcd * rowsPerX + within % rowsPerX) * 128;
    const int bn = (grp * grpW + within / rowsPerX) * 128;

    const char* aSrc[2];
    const char* bSrc[2];
    uint ldsOff[2];
#pragma unroll
    for (int it = 0; it < 2; ++it) {
        const int c = it * 256 + tid;          // 16B chunk id 0..511
        const int r = c >> 2;                  // tile row 0..127
        const int ch = c & 3;                  // chunk within row (K dir)
        const int sch = ch ^ ((r >> 1) & 3);   // swizzled source chunk
        aSrc[it] = (const char*)A + (size_t)(bm + r) * (DIM * 2) + sch * 16;
        bSrc[it] = (const char*)B + (size_t)(bn + r) * (DIM * 2) + sch * 16;
        ldsOff[it] = it * 4096 + (uint)(wid * 1024);
    }

    const int fr = lane & 15, fk = lane >> 4;
    const int swz = (fr >> 1) & 3;
    int idxA[4], idxB[4];
#pragma unroll
    for (int m = 0; m < 4; ++m)
        idxA[m] = (wr * 64 + m * 16 + fr) * 32 + ((fk ^ swz) * 8);
#pragma unroll
    for (int n = 0; n < 4; ++n)
        idxB[n] = (wc * 64 + n * 16 + fr) * 32 + ((fk ^ swz) * 8);

    f32x4 acc[4][4];
#pragma unroll
    for (int m = 0; m < 4; ++m)
#pragma unroll
        for (int n = 0; n < 4; ++n) acc[m][n] = (f32x4){0.f, 0.f, 0.f, 0.f};

    // 4 loads/thread per STAGE (A it0, B it0, A it1, B it1); slot b in 0..2
#define STAGE(b, ks)                                                               \
    {                                                                              \
        _Pragma("unroll") for (int it = 0; it < 2; ++it) {                         \
            gload_lds16(aSrc[it] + (ks) * 64,                                      \
                        (char*)smem + (b) * 8192 + ldsOff[it]);                    \
            gload_lds16(bSrc[it] + (ks) * 64,                                      \
                        (char*)smem + 24576 + (b) * 8192 + ldsOff[it]);            \
        }                                                                          \
    }

    // prologue: 2 stages in flight (8 outstanding loads/thread)
    STAGE(0, 0);
    STAGE(1, 1);

#pragma unroll
    for (int ks = 0; ks < KSTEPS; ++ks) {
        // wait for own stage-ks loads; keep the one younger stage in flight
        if (ks < KSTEPS - 1) { asm volatile("s_waitcnt vmcnt(4)" ::: "memory"); }
        else                 { asm volatile("s_waitcnt vmcnt(0)" ::: "memory"); }
        __builtin_amdgcn_s_barrier();          // all waves' stage-ks loads landed
        asm volatile("" ::: "memory");         // no LDS read hoists above barrier

        if (ks + 2 < KSTEPS) STAGE((ks + 2) % 3, ks + 2);  // refill ring slot

        const int slot = ks % 3;
        const ushort* sAc = smem + slot * 4096;
        const ushort* sBc = smem + 12288 + slot * 4096;
        bf16x8 av[4], bv[4];
#pragma unroll
        for (int m = 0; m < 4; ++m) av[m] = *(const bf16x8*)&sAc[idxA[m]];
#pragma unroll
        for (int n = 0; n < 4; ++n) bv[n] = *(const bf16x8*)&sBc[idxB[n]];
#pragma unroll
        for (int m = 0; m < 4; ++m)
#pragma unroll
            for (int n = 0; n < 4; ++n)
                acc[m][n] = __builtin_amdgcn_mfma_f32_16x16x32_bf16(av[m], bv[n], acc[m][n], 0, 0, 0);
    }
#undef STAGE

    // ---- epilogue: fragments -> ord16 LDS tile -> coalesced 16B stores ----
    __syncthreads();
#pragma unroll
    for (int m = 0; m < 4; ++m) {
#pragma unroll
        for (int n = 0; n < 4; ++n) {
            const int colb = wc * 64 + n * 16 + fr;
#pragma unroll
            for (int j = 0; j < 4; ++j) {
                const int rowb = wr * 64 + m * 16 + fk * 4 + j;
                smem[rowb * EPITCH + colb] = (ushort)bf2ord((uint)f2bf_rne(acc[m][n][j]));
            }
        }
    }
    __syncthreads();
    const int rr = tid >> 4, cc = (tid & 15) * 8;
#pragma unroll
    for (int it = 0; it < 8; ++it) {
        const int r = it * 16 + rr;
        uint4 v = *(const uint4*)&smem[r * EPITCH + cc];
        *(uint4*)(C + (size_t)(bm + r) * N + bn + cc) = v;
    }
}

// ---------------- wave-per-target: depth-4 scan + s1 + exact-detect ----------
// sim holds ord16. Keys: u32 = ord<<16 | (8191-idx) -> umax == (val desc, idx asc)
__global__ __launch_bounds__(256) void assign_score_w(const ushort* __restrict__ sim,
                                                      const int* __restrict__ labels,
                                                      const uchar* __restrict__ lab8,
                                                      const int* __restrict__ cstart,
                                                      const int* __restrict__ clist,
                                                      float* __restrict__ scores_out,
                                                      float* __restrict__ logt_out) {
    const int lane = threadIdx.x & 63, wid = threadIdx.x >> 6;
    const int t = blockIdx.x * 4 + wid;
    const ushort* row = sim + (size_t)t * NSRC;

    uint k0 = 0, k1 = 0, k2 = 0, k3 = 0, k4 = 0, k5 = 0, k6 = 0, k7 = 0;
    float s1 = 0.f;

#define CH4(u16, idx)                                                   \
    {                                                                   \
        uint uu = (uint)(u16);                                          \
        s1 += __expf(fmaf(ord2f(uu), INV_TAU, -INV_TAU));               \
        uint nk = (uu << 16) | (uint)(8191 - (idx));                    \
        uint q;                                                         \
        q = max(k0, nk); nk = min(k0, nk); k0 = q;                      \
        q = max(k1, nk); nk = min(k1, nk); k1 = q;                      \
        q = max(k2, nk); nk = min(k2, nk); k2 = q;                      \
        k3 = max(k3, nk);                                               \
    }
#define CH8(u16, idx)                                                   \
    {                                                                   \
        uint nk = (((uint)(u16)) << 16) | (uint)(8191 - (idx));         \
        uint q;                                                         \
        q = max(k0, nk); nk = min(k0, nk); k0 = q;                      \
        q = max(k1, nk); nk = min(k1, nk); k1 = q;                      \
        q = max(k2, nk); nk = min(k2, nk); k2 = q;                      \
        q = max(k3, nk); nk = min(k3, nk); k3 = q;                      \
        q = max(k4, nk); nk = min(k4, nk); k4 = q;                      \
        q = max(k5, nk); nk = min(k5, nk); k5 = q;                      \
        q = max(k6, nk); nk = min(k6, nk); k6 = q;                      \
        k7 = max(k7, nk);                                               \
    }
#define MERGE8                                                                     \
    _Pragma("unroll")                                                              \
    for (int d = 1; d < 64; d <<= 1) {                                             \
        uint b0 = __shfl_xor(k0, d), b1 = __shfl_xor(k1, d), b2 = __shfl_xor(k2, d),\
             b3 = __shfl_xor(k3, d), b4 = __shfl_xor(k4, d), b5 = __shfl_xor(k5, d),\
             b6 = __shfl_xor(k6, d), b7 = __shfl_xor(k7, d);                        \
        uint r0 = max(k0, b0);                                                     \
        uint r1 = max(max(min(k0, b0), k1), b1);                                   \
        uint r2 = max(max(min(k0, b1), min(k1, b0)), max(k2, b2));                 \
        uint r3 = max(max(min(k0, b2), min(k1, b1)),                               \
                      max(max(min(k2, b0), k3), b3));                              \
        uint r4 = max(max(max(min(k0, b3), min(k1, b2)),                           \
                          max(min(k2, b1), min(k3, b0))), max(k4, b4));            \
        uint r5 = max(max(max(min(k0, b4), min(k1, b3)),                           \
                          max(min(k2, b2), min(k3, b1))),                          \
                      max(max(min(k4, b0), k5), b5));                              \
        uint r6 = max(max(max(min(k0, b5), min(k1, b4)),                           \
                          max(min(k2, b3), min(k3, b2))),                          \
                      max(max(min(k4, b1), min(k5, b0)), max(k6, b6)));            \
        uint r7 = max(max(max(min(k0, b6), min(k1, b5)),                           \
                          max(min(k2, b4), min(k3, b3))),                          \
                      max(max(min(k4, b2), min(k5, b1)),                           \
                          max(max(min(k6, b0), k7), b7)));                         \
        k0 = r0; k1 = r1; k2 = r2; k3 = r3; k4 = r4; k5 = r5; k6 = r6; k7 = r7;    \
    }

    for (int i0 = lane * 8; i0 < NSRC; i0 += 512) {
        uint4 w = *(const uint4*)(row + i0);
        CH4(w.x & 0xFFFF, i0 + 0); CH4(w.x >> 16, i0 + 1);
        CH4(w.y & 0xFFFF, i0 + 2); CH4(w.y >> 16, i0 + 3);
        CH4(w.z & 0xFFFF, i0 + 4); CH4(w.z >> 16, i0 + 5);
        CH4(w.w & 0xFFFF, i0 + 6); CH4(w.w >> 16, i0 + 7);
    }
    const uint prek3 = k3;
    MERGE8;
    // exact iff every lane's dropped elems (< its pre-merge k3) are <= merged k7
    if (!__all((int)(prek3 <= k7))) {
        k0 = k1 = k2 = k3 = k4 = k5 = k6 = k7 = 0;
        for (int i0 = lane * 8; i0 < NSRC; i0 += 512) {
            uint4 w = *(const uint4*)(row + i0);
            CH8(w.x & 0xFFFF, i0 + 0); CH8(w.x >> 16, i0 + 1);
            CH8(w.y & 0xFFFF, i0 + 2); CH8(w.y >> 16, i0 + 3);
            CH8(w.z & 0xFFFF, i0 + 4); CH8(w.z >> 16, i0 + 5);
            CH8(w.w & 0xFFFF, i0 + 6); CH8(w.w >> 16, i0 + 7);
        }
        MERGE8;
    }
#undef CH4
#undef CH8
#undef MERGE8

    // s1 wave-reduce
#pragma unroll
    for (int d = 1; d < 64; d <<= 1) s1 += __shfl_xor(s1, d);

    // ---- labels of top-8 ----
    const int l0 = labels[8191 - (int)(k0 & 0xFFFF)];
    const int l1 = labels[8191 - (int)(k1 & 0xFFFF)];
    const int l2 = labels[8191 - (int)(k2 & 0xFFFF)];
    const int l3 = labels[8191 - (int)(k3 & 0xFFFF)];
    const int l4 = labels[8191 - (int)(k4 & 0xFFFF)];
    const int l5 = labels[8191 - (int)(k5 & 0xFFFF)];
    const int l6 = labels[8191 - (int)(k6 & 0xFFFF)];
    const int l7 = labels[8191 - (int)(k7 & 0xFFFF)];

    // ---- assigned = min label among modes of top-5 labels ----
    const int c0 = 1 + (l0 == l1) + (l0 == l2) + (l0 == l3) + (l0 == l4);
    const int c1 = (l1 == l0) + 1 + (l1 == l2) + (l1 == l3) + (l1 == l4);
    const int c2 = (l2 == l0) + (l2 == l1) + 1 + (l2 == l3) + (l2 == l4);
    const int c3 = (l3 == l0) + (l3 == l1) + (l3 == l2) + 1 + (l3 == l4);
    const int c4 = (l4 == l0) + (l4 == l1) + (l4 == l2) + (l4 == l3) + 1;
    const int maxc = max(max(max(c0, c1), max(c2, c3)), c4);
    int assigned = 0x7fffffff;
    if (c0 == maxc) assigned = min(assigned, l0);
    if (c1 == maxc) assigned = min(assigned, l1);
    if (c2 == maxc) assigned = min(assigned, l2);
    if (c3 == maxc) assigned = min(assigned, l3);
    if (c4 == maxc) assigned = min(assigned, l4);
    const int aL = assigned;

    // ---- nun: first-4 negatives (exact if <=4 positives in top-8) ----
    const int negcnt = (l0 != aL) + (l1 != aL) + (l2 != aL) + (l3 != aL) +
                       (l4 != aL) + (l5 != aL) + (l6 != aL) + (l7 != aL);
    float nun = 0.f;
    if (negcnt >= 4) {
        int c = 0;
#define NSTEP(kj, lj)                                                       \
        {                                                                   \
            bool take = ((lj) != aL) && (c < 4);                            \
            nun += take ? ord2f((kj) >> 16) : 0.f;                          \
            c += take ? 1 : 0;                                              \
        }
        NSTEP(k0, l0) NSTEP(k1, l1) NSTEP(k2, l2) NSTEP(k3, l3)
        NSTEP(k4, l4) NSTEP(k5, l5) NSTEP(k6, l6) NSTEP(k7, l7)
#undef NSTEP
    } else {
        // rare fallback: full-row top-4 negative chain in ord domain
        uint n0 = 0, n1 = 0, n2 = 0, n3 = 0;
        for (int i0 = lane * 8; i0 < NSRC; i0 += 512) {
            uint4 w = *(const uint4*)(row + i0);
            uint2 lw = *(const uint2*)(lab8 + i0);
#define NEGP(u16, lb)                                                       \
            {                                                               \
                uint x = ((lb) == aL) ? 0u : (uint)(u16);                   \
                uint q;                                                     \
                q = max(n0, x); x = min(n0, x); n0 = q;                     \
                q = max(n1, x); x = min(n1, x); n1 = q;                     \
                q = max(n2, x); x = min(n2, x); n2 = q;                     \
                n3 = max(n3, x);                                            \
            }
            NEGP(w.x & 0xFFFF, (int)(lw.x & 255));
            NEGP(w.x >> 16,    (int)((lw.x >> 8) & 255));
            NEGP(w.y & 0xFFFF, (int)((lw.x >> 16) & 255));
            NEGP(w.y >> 16,    (int)(lw.x >> 24));
            NEGP(w.z & 0xFFFF, (int)(lw.y & 255));
            NEGP(w.z >> 16,    (int)((lw.y >> 8) & 255));
            NEGP(w.w & 0xFFFF, (int)((lw.y >> 16) & 255));
            NEGP(w.w >> 16,    (int)(lw.y >> 24));
#undef NEGP
        }
#pragma unroll
        for (int d = 1; d < 64; d <<= 1) {
            uint b0 = __shfl_xor(n0, d), b1 = __shfl_xor(n1, d),
                 b2 = __shfl_xor(n2, d), b3 = __shfl_xor(n3, d);
            uint r0 = max(n0, b0);
            uint r1 = max(max(min(n0, b0), n1), b1);
            uint r2 = max(max(min(n0, b1), min(n1, b0)), max(n2, b2));
            uint r3 = max(max(min(n0, b2), min(n1, b1)),
                          max(max(min(n2, b0), n3), b3));
            n0 = r0; n1 = r1; n2 = r2; n3 = r3;
        }
        nun = (n0 ? ord2f(n0) : 0.f) + (n1 ? ord2f(n1) : 0.f) +
              (n2 ? ord2f(n2) : 0.f) + (n3 ? ord2f(n3) : 0.f);
    }

    // ---- class-member scan: top-4 positives + sp (gathered, ~128 elems) ----
    const int cs = cstart[aL], ce = cstart[aL + 1];
    float tp0 = -2.f, tp1 = -2.f, tp2 = -2.f, tp3 = -2.f;
    float sp = 0.f;
    for (int p = cs + lane; p < ce; p += 64) {
        const int idx = clist[p];
        float v = ord2f((uint)row[idx]);
        sp += __expf(fmaf(v, INV_TAU, -INV_TAU));
        float x = v, q;
        q = fmaxf(tp0, x); x = fminf(tp0, x); tp0 = q;
        q = fmaxf(tp1, x); x = fminf(tp1, x); tp1 = q;
        q = fmaxf(tp2, x); x = fminf(tp2, x); tp2 = q;
        tp3 = fmaxf(tp3, x);
    }
#pragma unroll
    for (int d = 1; d < 64; d <<= 1) {
        sp += __shfl_xor(sp, d);
        float b0 = __shfl_xor(tp0, d), b1 = __shfl_xor(tp1, d),
              b2 = __shfl_xor(tp2, d), b3 = __shfl_xor(tp3, d);
        float r0 = fmaxf(tp0, b0);
        float r1 = fmaxf(fmaxf(fminf(tp0, b0), tp1), b1);
        float r2 = fmaxf(fmaxf(fminf(tp0, b1), fminf(tp1, b0)), fmaxf(tp2, b2));
        float r3 = fmaxf(fmaxf(fminf(tp0, b2), fminf(tp1, b1)),
                         fmaxf(fmaxf(fminf(tp2, b0), tp3), b3));
        tp0 = r0; tp1 = r1; tp2 = r2; tp3 = r3;
    }

    if (lane == 0) {
        float nln = (tp0 > -1.5f ? tp0 : 0.f) + (tp1 > -1.5f ? tp1 : 0.f) +
                    (tp2 > -1.5f ? tp2 : 0.f) + (tp3 > -1.5f ? tp3 : 0.f);
        scores_out[t] = nln / nun;
        logt_out[t] = logf(sp / s1 + 1e-6f);
    }
}

// --------------------------------------- wave-per-element rank selection ----
__global__ __launch_bounds__(256) void select_topk_w(const float* __restrict__ scores,
                                                     int* __restrict__ selected,
                                                     int n, int k) {
    const int lane = threadIdx.x & 63, wid = threadIdx.x >> 6;
    const int t = blockIdx.x * 4 + wid;
    if (t >= n) return;
    const float st = scores[t];
    int rank = 0;
    for (int j0 = lane * 4; j0 < n; j0 += 256) {
        float4 v = *(const float4*)(scores + j0);
        rank += (v.x > st) || (v.x == st && (j0 + 0) < t);
        rank += (v.y > st) || (v.y == st && (j0 + 1) < t);
        rank += (v.z > st) || (v.z == st && (j0 + 2) < t);
        rank += (v.w > st) || (v.w == st && (j0 + 3) < t);
    }
    for (int d = 1; d < 64; d <<= 1) rank += __shfl_xor(rank, d);
    if (lane == 0) selected[t] = (rank < k) ? 1 : 0;
}

// ----------------------------------------------------------- finalize -------
__global__ __launch_bounds__(256) void finalize_k(const float* __restrict__ logt,
                                                  const int* __restrict__ selected,
                                                  float* __restrict__ out, int n, int k) {
    __shared__ float red[256];
    const int tid = threadIdx.x;
    float s = 0.f;
    for (int i = tid; i < n; i += 256) s += selected[i] ? logt[i] : 0.f;
    red[tid] = s;
    __syncthreads();
    for (int st = 128; st > 0; st >>= 1) {
        if (tid < st) red[tid] += red[tid + st];
        __syncthreads();
    }
    if (tid == 0) out[0] = -red[0] / (float)k;
}

// -------------------------------------------------------------- launch ------
extern "C" void kernel_launch(void* const* d_in, const int* in_sizes, int n_in,
                              void* d_out, int out_size, void* d_ws, size_t ws_size,
                              hipStream_t stream) {
    const float* srcF = (const float*)d_in[0];
    const int* labels = (const int*)d_in[1];
    const float* tgtF = (const float*)d_in[2];
    float* out = (float*)d_out;

    const int n_src = in_sizes[1];            // 8192
    const int d = in_sizes[0] / n_src;        // 256
    const int n_tgt = in_sizes[2] / d;        // 6144
    const int topn = n_tgt * 2 / 3;           // 4096

    char* ws = (char*)d_ws;
    ushort* src2 = (ushort*)ws;  ws += (size_t)n_src * DIM * sizeof(ushort);
    ushort* tgt2 = (ushort*)ws;  ws += (size_t)n_tgt * DIM * sizeof(ushort);
    ushort* sim  = (ushort*)ws;  ws += (size_t)n_tgt * NSRC * sizeof(ushort);
    float* scores = (float*)ws;  ws += (size_t)n_tgt * sizeof(float);
    float* logt   = (float*)ws;  ws += (size_t)n_tgt * sizeof(float);
    int* selected = (int*)ws;    ws += (size_t)n_tgt * sizeof(int);
    int* cstart   = (int*)ws;    ws += (size_t)(NCLS + 1) * sizeof(int);
    int* clist    = (int*)ws;    ws += (size_t)n_src * sizeof(int);
    uchar* lab8   = (uchar*)ws;  ws += (size_t)n_src;

    const int nrows = n_tgt + n_src;          // one wave per row, 4 waves/block
    l2bf2_k<<<(nrows + 3) / 4, 256, 0, stream>>>(tgtF, tgt2, n_tgt, srcF, src2, n_src);
    class_build_k<<<NCLS, 256, 0, stream>>>(labels, lab8, cstart, clist, n_src);

    dim3 grid(n_src / 128, n_tgt / 128);
    gemm_mfma_k<<<grid, 256, 0, stream>>>(tgt2, src2, sim, n_tgt, n_src);

    assign_score_w<<<n_tgt / 4, 256, 0, stream>>>(sim, labels, lab8, cstart, clist,
                                                  scores, logt);
    select_topk_w<<<(n_tgt + 3) / 4, 256, 0, stream>>>(scores, selected, n_tgt, topn);
    finalize_k<<<1, 256, 0, stream>>>(logt, selected, out, n_tgt, topn);
}